// Round 12
// baseline (27.986 us; speedup 1.0000x reference)
//
#include <hip/hip_runtime.h>
#include <math.h>

#define KC 3
#define NF 8
#define HH 480
#define WW 640
#define HWPIX (HH * WW)
#define FSTRIDE (HWPIX * 3)   // floats per frame plane

__device__ __forceinline__ float frcp(float x)  { return __builtin_amdgcn_rcpf(x); }
__device__ __forceinline__ float fexp2(float x) { return __builtin_amdgcn_exp2f(x); }
__device__ __forceinline__ float flog2(float x) { return __builtin_amdgcn_logf(x); }
__device__ __forceinline__ float fsqrtf(float x){ return __builtin_amdgcn_sqrtf(x); }
__device__ __forceinline__ float ffma(float a, float b, float c) { return __builtin_fmaf(a, b, c); }

struct Gmm {
    float m0[KC], m1[KC], m2[KC], dv[KC], wt[KC];
};

struct Acc {
    float rs[KC], mx[KC], my[KC], mz[KC], aq[KC];
};

__device__ __forceinline__ void acc_sample(Acc& a, float r0, float r1, float r2,
                                           float xa, float xb, float xc, float qq)
{
    a.rs[0] += r0;  a.mx[0] = ffma(r0, xa, a.mx[0]);  a.my[0] = ffma(r0, xb, a.my[0]);
    a.mz[0] = ffma(r0, xc, a.mz[0]);  a.aq[0] = ffma(r0, qq, a.aq[0]);
    a.rs[1] += r1;  a.mx[1] = ffma(r1, xa, a.mx[1]);  a.my[1] = ffma(r1, xb, a.my[1]);
    a.mz[1] = ffma(r1, xc, a.mz[1]);  a.aq[1] = ffma(r1, qq, a.aq[1]);
    a.rs[2] += r2;  a.mx[2] = ffma(r2, xa, a.mx[2]);  a.my[2] = ffma(r2, xb, a.my[2]);
    a.mz[2] = ffma(r2, xc, a.mz[2]);  a.aq[2] = ffma(r2, qq, a.aq[2]);
}

// M-step finalize from accumulators (shared by iter-1 and generic iters)
__device__ __forceinline__ void finalize(const Acc& a, Gmm& g)
{
    const float S_FLOOR = 1e-20f;
#pragma unroll
    for (int k = 0; k < KC; ++k) {
        const float invrs = frcp(a.rs[k]);          // garbage if starved; selected away
        const float n0 = a.mx[k] * invrs, n1 = a.my[k] * invrs, n2 = a.mz[k] * invrs;
        const float mm2 = ffma(n0, n0, ffma(n1, n1, n2 * n2));
        const float nd = ffma(a.aq[k], invrs, -mm2);  // Koenig identity
        const bool ok = a.rs[k] > S_FLOOR;
        g.m0[k] = ok ? n0 : g.m0[k];
        g.m1[k] = ok ? n1 : g.m1[k];
        g.m2[k] = ok ? n2 : g.m2[k];
        g.dv[k] = ok ? nd : g.dv[k];
        g.wt[k] = a.rs[k] * 0.125f;                 // rs/N — reference semantics
    }
}

// Generic EM iteration (iters 2..n): straight-line, register-resident.
__device__ __forceinline__ void em_iter(const float (&x0)[NF], const float (&x1)[NF],
                                        const float (&x2)[NF], const float (&q)[NF],
                                        Gmm& g)
{
    const float L2E = 1.4426950408889634f;   // log2(e)
    const float DEV_FLOOR = 1e-12f;
    const float E_FLOOR = -1e18f;
    const float D_CLAMP = 126.0f;

    float A[KC], B2[KC];
#pragma unroll
    for (int k = 0; k < KC; ++k) {
        const float invd = frcp(fmaxf(g.dv[k], DEV_FLOOR));
        const float a2 = (-0.5f * L2E) * invd * invd;
        const float mm = ffma(g.m0[k], g.m0[k], ffma(g.m1[k], g.m1[k], g.m2[k] * g.m2[k]));
        const float lg = flog2(g.wt[k] * invd);  // wt=0 -> -inf; floored below
        A[k] = a2;
        B2[k] = ffma(a2, mm, lg);
    }

    Acc ac;
#pragma unroll
    for (int k = 0; k < KC; ++k) { ac.rs[k] = ac.mx[k] = ac.my[k] = ac.mz[k] = ac.aq[k] = 0.0f; }

#pragma unroll
    for (int n = 0; n < NF; ++n) {
        const float xa = x0[n], xb = x1[n], xc = x2[n], qq = q[n];
        float e[KC];
#pragma unroll
        for (int k = 0; k < KC; ++k) {
            const float t = ffma(g.m0[k], xa, ffma(g.m1[k], xb, g.m2[k] * xc));
            const float u = ffma(-2.0f, t, qq);
            e[k] = fmaxf(ffma(A[k], u, B2[k]), E_FLOOR);   // finite always
        }
        // pivoted softmax on component 2: only 2 exps per sample.
        const float d0 = fminf(e[0] - e[2], D_CLAMP);
        const float d1 = fminf(e[1] - e[2], D_CLAMP);
        const float p0 = fexp2(d0);
        const float p1 = fexp2(d1);
        const float sinv = frcp(p0 + p1 + 1.0f);   // s in [1, 2^127] -> finite
        acc_sample(ac, p0 * sinv, p1 * sinv, sinv, xa, xb, xc, qq);
    }

    finalize(ac, g);
}

__global__ __launch_bounds__(256, 4) void gmm_fit_process_kernel(
    const float* __restrict__ frames,   // [N,H,W,3]
    const float* __restrict__ frame,    // [H,W,3]
    const int* __restrict__ n_iter_p,
    float* __restrict__ out)            // [2,H,W]
{
    const int p = blockIdx.x * 256 + threadIdx.x;  // grid covers HWPIX exactly
    const int n_iter = *n_iter_p;

    const float* fr = frame + (size_t)p * 3;
    const float fx = fr[0], fy = fr[1], fz = fr[2];

    // ================== ITERATION 1, fused with the load stream ==================
    // Init state is compile-time: mean_k = (k+1)/4 (all comps), dev = 1, w = 1/3.
    // With dev=1 the exponent scale A is SHARED across components, so the pivoted
    // exponent differences collapse to affine functions of sx = xa+xb+xc:
    //   e0-e2 = A*sx*1.0 + A*(mm0-mm2),  e1-e2 = A*sx*0.5 + A*(mm1-mm2)
    // (mm_k = ||mean_k||^2 = {0.1875, 0.75, 1.6875}); weights equal -> cancel.
    const float A1   = -0.72134752044448170f;   // -0.5*log2(e)
    const float DB0  =  1.08202128066672260f;   // A1*(0.1875-1.6875)
    const float DB1  =  0.67626330041670160f;   // A1*0.5 ... slope for d1
    // d0 = A1*sx + DB0 ; d1 = (A1*0.5)*sx + DB0*?  -- careful: separate consts:
    const float SL0  = A1;                       // slope for d0
    const float SL1  = 0.5f * A1;                // slope for d1
    const float OF1  = A1 * (0.75f - 1.6875f);   // = 0.67626330 (offset for d1)

    float x0[NF], x1[NF], x2[NF], q[NF];
    Acc ac;
#pragma unroll
    for (int k = 0; k < KC; ++k) { ac.rs[k] = ac.mx[k] = ac.my[k] = ac.mz[k] = ac.aq[k] = 0.0f; }

    {
        const float* base = frames + (size_t)p * 3;
        // process each sample as it arrives: compiler stages s_waitcnt vmcnt(N)
        // so iter-1 compute overlaps the remaining in-flight loads.
#pragma unroll
        for (int n = 0; n < NF; ++n) {
            const float* s = base + (size_t)n * FSTRIDE;
            x0[n] = s[0]; x1[n] = s[1]; x2[n] = s[2];
        }
#pragma unroll
        for (int n = 0; n < NF; ++n) {
            const float xa = x0[n], xb = x1[n], xc = x2[n];
            const float qq = ffma(xa, xa, ffma(xb, xb, xc * xc));
            q[n] = qq;
            const float sx = xa + xb + xc;
            const float d0 = ffma(SL0, sx, DB0);     // bounded: sx in [0,3)
            const float d1 = ffma(SL1, sx, OF1);
            const float p0 = fexp2(d0);
            const float p1 = fexp2(d1);
            const float sinv = frcp(p0 + p1 + 1.0f);
            acc_sample(ac, p0 * sinv, p1 * sinv, sinv, xa, xb, xc, qq);
        }
    }

    Gmm g;
#pragma unroll
    for (int k = 0; k < KC; ++k) {
        const float m0 = (float)(k + 1) / 4.0f;
        g.m0[k] = m0; g.m1[k] = m0; g.m2[k] = m0;
        g.dv[k] = 1.0f;
        g.wt[k] = 1.0f / 3.0f;
    }

    if (n_iter >= 1) {
        finalize(ac, g);   // completes iteration 1
        if (n_iter == 5) {
#pragma unroll
            for (int it = 1; it < 5; ++it) em_iter(x0, x1, x2, q, g);
        } else {
            for (int it = 1; it < n_iter; ++it) em_iter(x0, x1, x2, q, g);
        }
    }

    // ---- fg ratio ----
    const float DEV_FLOOR = 1e-12f;
    float ratio[KC];
    float rmin = 3.402823466e+38f;
#pragma unroll
    for (int k = 0; k < KC; ++k) {
        ratio[k] = g.wt[k] * frcp(fmaxf(g.dv[k], DEV_FLOOR));
        rmin = fminf(rmin, ratio[k]);
    }

    // ---- classify test pixel ----
    float mind = 3.402823466e+38f;
    int index = 0;
#pragma unroll
    for (int k = 0; k < KC; ++k) {
        const float dx = fx - g.m0[k];
        const float dy = fy - g.m1[k];
        const float dz = fz - g.m2[k];
        const float dist = fsqrtf(ffma(dx, dx, ffma(dy, dy, dz * dz)));
        if (dist < mind) { mind = dist; index = k; }  // first-min (jnp.argmin)
    }

    out[p] = (ratio[index] <= rmin) ? 255.0f : 0.0f;
    out[HWPIX + p] = isfinite(mind) ? mind : 0.0f;
}

extern "C" void kernel_launch(void* const* d_in, const int* in_sizes, int n_in,
                              void* d_out, int out_size, void* d_ws, size_t ws_size,
                              hipStream_t stream) {
    const float* frames = (const float*)d_in[0];
    const float* frame  = (const float*)d_in[1];
    const int*   n_iter = (const int*)d_in[2];
    float* out = (float*)d_out;

    const int threads = 256;
    const int blocks = HWPIX / threads;  // 1200 workgroups, exact cover
    gmm_fit_process_kernel<<<blocks, threads, 0, stream>>>(frames, frame, n_iter, out);
}

// Round 13
// 23.858 us; speedup vs baseline: 1.1730x; 1.1730x over previous
//
#include <hip/hip_runtime.h>
#include <math.h>

#define KC 3
#define NF 8
#define HH 480
#define WW 640
#define HWPIX (HH * WW)
#define FSTRIDE (HWPIX * 3)   // floats per frame plane

__device__ __forceinline__ float frcp(float x)  { return __builtin_amdgcn_rcpf(x); }
__device__ __forceinline__ float fexp2(float x) { return __builtin_amdgcn_exp2f(x); }
__device__ __forceinline__ float flog2(float x) { return __builtin_amdgcn_logf(x); }
__device__ __forceinline__ float fsqrtf(float x){ return __builtin_amdgcn_sqrtf(x); }
__device__ __forceinline__ float ffma(float a, float b, float c) { return __builtin_fmaf(a, b, c); }

struct Gmm {
    float m0[KC], m1[KC], m2[KC], dv[KC], wt[KC];
};

// One EM iteration. All arrays fully unrolled -> registers.
__device__ __forceinline__ void em_iter(const float (&x0)[NF], const float (&x1)[NF],
                                        const float (&x2)[NF], const float (&q)[NF],
                                        Gmm& g)
{
    const float L2E = 1.4426950408889634f;   // log2(e)
    const float DEV_FLOOR = 1e-12f;
    const float S_FLOOR = 1e-20f;

    // per-component constants: e_k(n) = A_k*(q - 2*dot) + B2_k
    //   A_k = -0.5*log2(e)/dev_k ; B2_k = A_k*||m_k||^2 + log2(w_k*invd_k)
    float A[KC], B2[KC];
#pragma unroll
    for (int k = 0; k < KC; ++k) {
        const float invd = frcp(fmaxf(g.dv[k], DEV_FLOOR));
        const float a2 = (-0.5f * L2E) * invd * invd;
        const float mm = ffma(g.m0[k], g.m0[k], ffma(g.m1[k], g.m1[k], g.m2[k] * g.m2[k]));
        const float lg = flog2(g.wt[k] * invd);  // w=0 -> -inf -> r=0 (finite path)
        A[k] = a2;
        B2[k] = ffma(a2, mm, lg);
    }

    float rs[KC], mx[KC], my[KC], mz[KC], aq[KC];
#pragma unroll
    for (int k = 0; k < KC; ++k) { rs[k] = mx[k] = my[k] = mz[k] = aq[k] = 0.0f; }

#pragma unroll
    for (int n = 0; n < NF; ++n) {
        const float xa = x0[n], xb = x1[n], xc = x2[n], qq = q[n];
        float r[KC];
#pragma unroll
        for (int k = 0; k < KC; ++k) {
            const float t = ffma(g.m0[k], xa, ffma(g.m1[k], xb, g.m2[k] * xc));
            const float u = ffma(-2.0f, t, qq);
            r[k] = fexp2(ffma(A[k], u, B2[k]));
        }
        const float s = r[0] + r[1] + r[2];
        const float sinv = (s > S_FLOOR) ? frcp(s) : 0.0f;
#pragma unroll
        for (int k = 0; k < KC; ++k) {
            const float rk = r[k] * sinv;
            rs[k] += rk;
            mx[k] = ffma(rk, xa, mx[k]);
            my[k] = ffma(rk, xb, my[k]);
            mz[k] = ffma(rk, xc, mz[k]);
            aq[k] = ffma(rk, qq, aq[k]);
        }
    }

#pragma unroll
    for (int k = 0; k < KC; ++k) {
        const float invrs = frcp(rs[k]);          // garbage if starved; selected away
        const float n0 = mx[k] * invrs, n1 = my[k] * invrs, n2 = mz[k] * invrs;
        const float mm2 = ffma(n0, n0, ffma(n1, n1, n2 * n2));
        const float nd = ffma(aq[k], invrs, -mm2);  // Koenig identity
        const bool ok = rs[k] > S_FLOOR;
        g.m0[k] = ok ? n0 : g.m0[k];
        g.m1[k] = ok ? n1 : g.m1[k];
        g.m2[k] = ok ? n2 : g.m2[k];
        g.dv[k] = ok ? nd : g.dv[k];
        g.wt[k] = rs[k] * 0.125f;                 // rs/N — reference semantics
    }
}

__global__ __launch_bounds__(64, 4) void gmm_fit_process_kernel(
    const float* __restrict__ frames,   // [N,H,W,3]
    const float* __restrict__ frame,    // [H,W,3]
    const int* __restrict__ n_iter_p,
    float* __restrict__ out)            // [2,H,W]
{
    const int p = blockIdx.x * 64 + threadIdx.x;   // one pixel per thread, exact cover
    const int n_iter = *n_iter_p;

    // ---- issue ALL independent loads first (overlap latency with init) ----
    const float* fr = frame + (size_t)p * 3;
    const float fx = fr[0], fy = fr[1], fz = fr[2];

    float x0[NF], x1[NF], x2[NF], q[NF];
    {
        const float* base = frames + (size_t)p * 3;
#pragma unroll
        for (int n = 0; n < NF; ++n) {
            const float* s = base + (size_t)n * FSTRIDE;
            x0[n] = s[0]; x1[n] = s[1]; x2[n] = s[2];
        }
#pragma unroll
        for (int n = 0; n < NF; ++n)
            q[n] = ffma(x0[n], x0[n], ffma(x1[n], x1[n], x2[n] * x2[n]));
    }

    // ---- init GMM state ----
    Gmm g;
#pragma unroll
    for (int k = 0; k < KC; ++k) {
        const float m0 = (float)(k + 1) / 4.0f;
        g.m0[k] = m0; g.m1[k] = m0; g.m2[k] = m0;
        g.dv[k] = 1.0f;
        g.wt[k] = 1.0f / 3.0f;
    }

    if (n_iter == 5) {
#pragma unroll
        for (int it = 0; it < 5; ++it) em_iter(x0, x1, x2, q, g);
    } else {
        for (int it = 0; it < n_iter; ++it) em_iter(x0, x1, x2, q, g);
    }

    // ---- fg ratio ----
    const float DEV_FLOOR = 1e-12f;
    float ratio[KC];
    float rmin = 3.402823466e+38f;
#pragma unroll
    for (int k = 0; k < KC; ++k) {
        ratio[k] = g.wt[k] * frcp(fmaxf(g.dv[k], DEV_FLOOR));
        rmin = fminf(rmin, ratio[k]);
    }

    // ---- classify test pixel ----
    float mind = 3.402823466e+38f;
    int index = 0;
#pragma unroll
    for (int k = 0; k < KC; ++k) {
        const float dx = fx - g.m0[k];
        const float dy = fy - g.m1[k];
        const float dz = fz - g.m2[k];
        const float dist = fsqrtf(ffma(dx, dx, ffma(dy, dy, dz * dz)));
        if (dist < mind) { mind = dist; index = k; }  // first-min (jnp.argmin)
    }

    out[p] = (ratio[index] <= rmin) ? 255.0f : 0.0f;
    out[HWPIX + p] = isfinite(mind) ? mind : 0.0f;
}

extern "C" void kernel_launch(void* const* d_in, const int* in_sizes, int n_in,
                              void* d_out, int out_size, void* d_ws, size_t ws_size,
                              hipStream_t stream) {
    const float* frames = (const float*)d_in[0];
    const float* frame  = (const float*)d_in[1];
    const int*   n_iter = (const int*)d_in[2];
    float* out = (float*)d_out;

    const int threads = 64;
    const int blocks = HWPIX / threads;  // 4800 waves, exact cover
    gmm_fit_process_kernel<<<blocks, threads, 0, stream>>>(frames, frame, n_iter, out);
}